// Round 1
// baseline (1245.193 us; speedup 1.0000x reference)
//
#include <hip/hip_runtime.h>
#include <stdint.h>

#define N 8192
#define G 7
#define T 512   // threads per block; N/2/T = 8 pairs per thread per pass

// Map float bits -> uint32 such that ascending uint order == DESCENDING float
// order, with XLA total-order semantics (+0 before -0 in descending view).
__device__ __forceinline__ uint32_t enc_desc(float x) {
    uint32_t u = __float_as_uint(x);
    return (u & 0x80000000u) ? u : (~u & 0x7FFFFFFFu);
}
__device__ __forceinline__ float dec_desc(uint32_t k) {
    uint32_t u = (k & 0x80000000u) ? k : (~k & 0x7FFFFFFFu);
    return __uint_as_float(u);
}

__global__ __launch_bounds__(T) void portfolio_sort_kernel(
    const float* __restrict__ x,
    float* __restrict__ bc,        // [B, N] float32
    float* __restrict__ idx_out)   // [B, N] indices stored as float32 (exact, < 2^24)
{
    __shared__ unsigned long long keys[N];  // 64 KiB

    const int row = blockIdx.x;
    const float* xr = x + (size_t)row * N;

    // ---- load + encode: key = (desc_order_key << 32) | original_index ----
    #pragma unroll
    for (int c = threadIdx.x; c < N; c += T) {
        float v = xr[c];
        keys[c] = ((unsigned long long)enc_desc(v) << 32) | (uint32_t)c;
    }
    __syncthreads();

    // ---- bitonic sort, ascending in key => descending in x, stable ties ----
    for (int k = 2; k <= N; k <<= 1) {
        for (int j = k >> 1; j > 0; j >>= 1) {
            #pragma unroll
            for (int p = threadIdx.x; p < N / 2; p += T) {
                int i = ((p & ~(j - 1)) << 1) | (p & (j - 1)); // bit j of i is 0
                int partner = i | j;
                unsigned long long a = keys[i];
                unsigned long long b = keys[partner];
                bool desc_block = (i & k) != 0;
                bool swap = desc_block ? (a < b) : (a > b);
                if (swap) { keys[i] = b; keys[partner] = a; }
            }
            __syncthreads();
        }
    }

    // ---- outputs ----
    float* bcr = bc + (size_t)row * N;
    float* ixr = idx_out + (size_t)row * N;

    // indices (coalesced) + zeros for the middle of b_c
    #pragma unroll
    for (int c = threadIdx.x; c < N; c += T) {
        unsigned long long kk = keys[c];
        ixr[c] = (float)(uint32_t)(kk & 0xFFFFFFFFu);
        if (c >= G && c < N - G) bcr[c] = 0.0f;
    }

    // winner: softmax over top-G sorted values (thread 0)
    if (threadIdx.x == 0) {
        float s[G], e[G];
        #pragma unroll
        for (int g = 0; g < G; ++g) s[g] = dec_desc((uint32_t)(keys[g] >> 32));
        float m = s[0];  // max (descending order)
        float sum = 0.f;
        #pragma unroll
        for (int g = 0; g < G; ++g) { e[g] = expf(s[g] - m); sum += e[g]; }
        #pragma unroll
        for (int g = 0; g < G; ++g) bcr[g] = e[g] / sum;
    }
    // loser: -softmax(1 - bottom-G) == -softmax(-bottom-G)  (thread 1)
    if (threadIdx.x == 1) {
        float s[G], e[G];
        #pragma unroll
        for (int g = 0; g < G; ++g) s[g] = dec_desc((uint32_t)(keys[N - G + g] >> 32));
        float m = -s[G - 1];  // max of (-s): s is descending, so -s ascending
        float sum = 0.f;
        #pragma unroll
        for (int g = 0; g < G; ++g) { e[g] = expf(-s[g] - m); sum += e[g]; }
        #pragma unroll
        for (int g = 0; g < G; ++g) bcr[N - G + g] = -e[g] / sum;
    }
}

extern "C" void kernel_launch(void* const* d_in, const int* in_sizes, int n_in,
                              void* d_out, int out_size, void* d_ws, size_t ws_size,
                              hipStream_t stream) {
    const float* x = (const float*)d_in[0];
    float* out = (float*)d_out;
    const int B = in_sizes[0] / N;               // 4096
    float* bc = out;                              // output 0: [B, N] float32
    float* idx = out + (size_t)B * N;             // output 1: [B, N] indices (as float32)
    portfolio_sort_kernel<<<B, T, 0, stream>>>(x, bc, idx);
}

// Round 2
// 817.768 us; speedup vs baseline: 1.5227x; 1.5227x over previous
//
#include <hip/hip_runtime.h>
#include <stdint.h>

#define N 8192
#define G 7
#define T 512          // threads per block; 16 elements per thread
typedef unsigned long long u64;

// Map float bits -> uint32 such that ascending uint order == DESCENDING float
// order, XLA total-order semantics. Stable ties via packed original index.
__device__ __forceinline__ uint32_t enc_desc(float x) {
    uint32_t u = __float_as_uint(x);
    return (u & 0x80000000u) ? u : (~u & 0x7FFFFFFFu);
}
__device__ __forceinline__ float dec_desc(uint32_t k) {
    uint32_t u = (k & 0x80000000u) ? k : (~k & 0x7FFFFFFFu);
    return __uint_as_float(u);
}

// XOR swizzle: permutes elements within each aligned 16-block so that
// fixed-register-slot accesses across a wave spread over 16 bank-pairs.
__device__ __forceinline__ int phys(int e) {
    return (e & ~15) | ((e ^ (e >> 4)) & 15);
}

// One bitonic compare-exchange pass over the 16 in-register elements.
// R = owned-bit index of the stride (stride j = 1<<(S+R)); kk = stage size.
// Global index of an element: base_e | (l << S). Ascending iff (i & kk)==0.
template<int R, int S>
__device__ __forceinline__ void bpass(u64* key, int base_e, int kk) {
#pragma unroll
    for (int h = 0; h < 8; ++h) {
        const int l = ((h >> R) << (R + 1)) | (h & ((1 << R) - 1)); // bit R clear
        const int m = l | (1 << R);
        bool desc = ((base_e | (l << S)) & kk) != 0;
        u64 a = key[l], b = key[m];
        u64 lo = (a < b) ? a : b;
        u64 hi = (a < b) ? b : a;
        key[l] = desc ? hi : lo;
        key[m] = desc ? lo : hi;
    }
}

// Ownership: thread t owns the 16 indices with bits S..S+3 free, other 9 bits
// from t (low S bits, then high bits shifted past the owned nibble).
template<int S>
__device__ __forceinline__ int sbase(int t) {
    return (t & ((1 << S) - 1)) | ((t >> S) << (S + 4));
}
template<int S>
__device__ __forceinline__ void sload(u64* key, const u64* lds, int base) {
#pragma unroll
    for (int l = 0; l < 16; ++l) key[l] = lds[phys(base | (l << S))];
}
template<int S>
__device__ __forceinline__ void sstore(const u64* key, u64* lds, int base) {
#pragma unroll
    for (int l = 0; l < 16; ++l) lds[phys(base | (l << S))] = key[l];
}

__global__ __launch_bounds__(T) void portfolio_sort_kernel(
    const float* __restrict__ x,
    float* __restrict__ bc,        // [B, N] float32
    float* __restrict__ idx_out)   // [B, N] indices stored as float32
{
    __shared__ u64 lds[N];         // 64 KiB
    const int t = threadIdx.x;
    const int row = blockIdx.x;
    const float* xr = x + (size_t)row * N;

    // ---- load + encode (float4 global reads, swizzled LDS writes) ----
#pragma unroll
    for (int i = 0; i < 4; ++i) {
        int e = 4 * t + 2048 * i;
        float4 v = *(const float4*)(xr + e);
        lds[phys(e + 0)] = ((u64)enc_desc(v.x) << 32) | (uint32_t)(e + 0);
        lds[phys(e + 1)] = ((u64)enc_desc(v.y) << 32) | (uint32_t)(e + 1);
        lds[phys(e + 2)] = ((u64)enc_desc(v.z) << 32) | (uint32_t)(e + 2);
        lds[phys(e + 3)] = ((u64)enc_desc(v.w) << 32) | (uint32_t)(e + 3);
    }
    __syncthreads();

    u64 key[16];

    // ---- session 1: stages k=2,4,8,16 fully in registers ----
    {
        int base = sbase<0>(t);
        sload<0>(key, lds, base);
        bpass<0,0>(key, base, 2);
        bpass<1,0>(key, base, 4);  bpass<0,0>(key, base, 4);
        bpass<2,0>(key, base, 8);  bpass<1,0>(key, base, 8);  bpass<0,0>(key, base, 8);
        bpass<3,0>(key, base, 16); bpass<2,0>(key, base, 16); bpass<1,0>(key, base, 16); bpass<0,0>(key, base, 16);
        sstore<0>(key, lds, base);
    }
    __syncthreads();

    // ---- stages k = 32..256: [S=4 session] [S=0 session] ----
    for (int k = 32; k <= 256; k <<= 1) {
        {
            int base = sbase<4>(t);
            sload<4>(key, lds, base);
            if (k >= 256) bpass<3,4>(key, base, k);
            if (k >= 128) bpass<2,4>(key, base, k);
            if (k >= 64)  bpass<1,4>(key, base, k);
            bpass<0,4>(key, base, k);
            sstore<4>(key, lds, base);
        }
        __syncthreads();
        {
            int base = sbase<0>(t);
            sload<0>(key, lds, base);
            bpass<3,0>(key, base, k); bpass<2,0>(key, base, k);
            bpass<1,0>(key, base, k); bpass<0,0>(key, base, k);
            sstore<0>(key, lds, base);
        }
        __syncthreads();
    }

    // ---- stages k = 512..4096: [S=8] [S=4] [S=0] ----
    for (int k = 512; k <= 4096; k <<= 1) {
        {
            int base = sbase<8>(t);
            sload<8>(key, lds, base);
            if (k >= 4096) bpass<3,8>(key, base, k);
            if (k >= 2048) bpass<2,8>(key, base, k);
            if (k >= 1024) bpass<1,8>(key, base, k);
            bpass<0,8>(key, base, k);
            sstore<8>(key, lds, base);
        }
        __syncthreads();
        {
            int base = sbase<4>(t);
            sload<4>(key, lds, base);
            bpass<3,4>(key, base, k); bpass<2,4>(key, base, k);
            bpass<1,4>(key, base, k); bpass<0,4>(key, base, k);
            sstore<4>(key, lds, base);
        }
        __syncthreads();
        {
            int base = sbase<0>(t);
            sload<0>(key, lds, base);
            bpass<3,0>(key, base, k); bpass<2,0>(key, base, k);
            bpass<1,0>(key, base, k); bpass<0,0>(key, base, k);
            sstore<0>(key, lds, base);
        }
        __syncthreads();
    }

    // ---- stage k = 8192: [S=9: stride 4096] [S=8] [S=4] [S=0 final, no store] ----
    {
        int base = sbase<9>(t);          // == t; elements t | (l<<9)
        sload<9>(key, lds, base);
        bpass<3,9>(key, base, 8192);     // stride 4096 (bit 12); always ascending
        sstore<9>(key, lds, base);
    }
    __syncthreads();
    {
        int base = sbase<8>(t);
        sload<8>(key, lds, base);
        bpass<3,8>(key, base, 8192); bpass<2,8>(key, base, 8192);
        bpass<1,8>(key, base, 8192); bpass<0,8>(key, base, 8192);
        sstore<8>(key, lds, base);
    }
    __syncthreads();
    {
        int base = sbase<4>(t);
        sload<4>(key, lds, base);
        bpass<3,4>(key, base, 8192); bpass<2,4>(key, base, 8192);
        bpass<1,4>(key, base, 8192); bpass<0,4>(key, base, 8192);
        sstore<4>(key, lds, base);
    }
    __syncthreads();

    // final S=0 session: thread t ends holding sorted[16t .. 16t+15] in regs
    {
        int base = sbase<0>(t);          // = t << 4
        sload<0>(key, lds, base);
        bpass<3,0>(key, base, 8192); bpass<2,0>(key, base, 8192);
        bpass<1,0>(key, base, 8192); bpass<0,0>(key, base, 8192);

        float* bcr = bc + (size_t)row * N;
        float* ixr = idx_out + (size_t)row * N;

        // indices straight from registers, float4 stores
        float iv[16];
#pragma unroll
        for (int l = 0; l < 16; ++l) iv[l] = (float)(uint32_t)(key[l] & 0xFFFFFFFFu);
#pragma unroll
        for (int q = 0; q < 4; ++q)
            *(float4*)(ixr + base + 4 * q) =
                make_float4(iv[4*q], iv[4*q+1], iv[4*q+2], iv[4*q+3]);

        // b_c: zeros except winner (thread 0, l=0..6) and loser (thread T-1, l=9..15)
        float bv[16];
#pragma unroll
        for (int l = 0; l < 16; ++l) bv[l] = 0.0f;

        if (t == 0) {
            float s[G], ex[G], sum = 0.f;
#pragma unroll
            for (int g = 0; g < G; ++g) s[g] = dec_desc((uint32_t)(key[g] >> 32));
            float m = s[0];  // max (descending order)
#pragma unroll
            for (int g = 0; g < G; ++g) { ex[g] = expf(s[g] - m); sum += ex[g]; }
#pragma unroll
            for (int g = 0; g < G; ++g) bv[g] = ex[g] / sum;
        }
        if (t == T - 1) {
            // loser = -softmax(1 - bottom) == -softmax(-bottom)
            float s[G], ex[G], sum = 0.f;
#pragma unroll
            for (int g = 0; g < G; ++g) s[g] = dec_desc((uint32_t)(key[9 + g] >> 32));
            float m = -s[G - 1];  // max of -s (s descending)
#pragma unroll
            for (int g = 0; g < G; ++g) { ex[g] = expf(-s[g] - m); sum += ex[g]; }
#pragma unroll
            for (int g = 0; g < G; ++g) bv[9 + g] = -ex[g] / sum;
        }
#pragma unroll
        for (int q = 0; q < 4; ++q)
            *(float4*)(bcr + base + 4 * q) =
                make_float4(bv[4*q], bv[4*q+1], bv[4*q+2], bv[4*q+3]);
    }
}

extern "C" void kernel_launch(void* const* d_in, const int* in_sizes, int n_in,
                              void* d_out, int out_size, void* d_ws, size_t ws_size,
                              hipStream_t stream) {
    const float* x = (const float*)d_in[0];
    float* out = (float*)d_out;
    const int B = in_sizes[0] / N;               // 4096
    float* bc = out;                              // output 0: [B, N]
    float* idx = out + (size_t)B * N;             // output 1: [B, N] (as float32)
    portfolio_sort_kernel<<<B, T, 0, stream>>>(x, bc, idx);
}

// Round 3
// 588.197 us; speedup vs baseline: 2.1170x; 1.3903x over previous
//
#include <hip/hip_runtime.h>
#include <stdint.h>

#define N 8192
#define G 7
#define T 512
#define NW 8          // waves per block
typedef unsigned long long u64;
typedef uint32_t u32;

// Map float bits -> uint32 such that ascending uint order == DESCENDING float
// order, XLA total-order semantics. Stable LSD radix handles index tie-break.
__device__ __forceinline__ u32 enc_desc(float x) {
    u32 u = __float_as_uint(x);
    return (u & 0x80000000u) ? u : (~u & 0x7FFFFFFFu);
}
__device__ __forceinline__ float dec_desc(u32 k) {
    u32 u = (k & 0x80000000u) ? k : (~k & 0x7FFFFFFFu);
    return __uint_as_float(u);
}

__global__ __launch_bounds__(T) void portfolio_radix_kernel(
    const float* __restrict__ x,
    float* __restrict__ bc,        // [B, N] float32
    float* __restrict__ idx_out)   // [B, N] indices as float32
{
    __shared__ u64 data[N];          // 64 KiB
    __shared__ u32 wcnt[NW * 256];   // 8 KiB  per-wave digit counters / bases
    __shared__ u32 dsum[256];        // 1 KiB  global digit exclusive bases
    __shared__ u32 wsum[4];          // chunk sums for 256-wide scan

    const int t    = threadIdx.x;
    const int w    = t >> 6;         // wave 0..7
    const int lane = t & 63;
    const int row  = blockIdx.x;
    const float* xr = x + (size_t)row * N;

    const u64 below = (1ull << lane) - 1ull;

    // Element ownership: e = 1024*w + 64*j + lane  (order = (w, j, lane), which
    // matches the rank composition: wave-base + earlier-slot counts + lane rank)
    u64 key[16];
#pragma unroll
    for (int j = 0; j < 16; ++j) {
        int e = (w << 10) | (j << 6) | lane;
        key[j] = ((u64)enc_desc(xr[e]) << 32) | (u32)e;
    }

    u32 rank[16];

    for (int p = 0; p < 4; ++p) {
        const int shift = 32 + 8 * p;

        // ---- zero per-wave counters ----
#pragma unroll
        for (int i = 0; i < 4; ++i) wcnt[t + T * i] = 0;
        __syncthreads();

        // ---- phase A: stable in-wave rank + per-wave histogram ----
#pragma unroll
        for (int j = 0; j < 16; ++j) {
            u32 d = (u32)(key[j] >> shift) & 255u;
            u64 m = ~0ull;                       // lanes with same digit
#pragma unroll
            for (int b = 0; b < 8; ++b) {
                u64 bb = __ballot(d & (1u << b));
                m &= (d & (1u << b)) ? bb : ~bb;
            }
            u32 r    = (u32)__popcll(m & below); // rank among group, lane order
            u32 base = wcnt[(w << 8) | d];       // broadcast read (same addr in group)
            rank[j] = base + r;
            if (r == 0)                          // group leader updates counter
                wcnt[(w << 8) | d] = base + (u32)__popcll(m);
        }
        __syncthreads();

        // ---- phase B: scan. threads 0..255 own one digit each ----
        if (t < 256) {
            u32 run = 0;
#pragma unroll
            for (int ww = 0; ww < NW; ++ww) {    // serial over waves: exclusive
                u32 c = wcnt[(ww << 8) | t];     // per-wave base for this digit
                wcnt[(ww << 8) | t] = run;
                run += c;
            }
            // run = total count of digit t; shuffle inclusive scan over 64 digits
            u32 v = run;
#pragma unroll
            for (int off = 1; off < 64; off <<= 1) {
                u32 u = __shfl_up(v, off, 64);
                if (lane >= off) v += u;
            }
            if (lane == 63) wsum[w] = v;         // chunk total (w = 0..3 here)
            dsum[t] = v - run;                   // exclusive within chunk
        }
        __syncthreads();
        if (t < 256) {
            u32 add = 0;
            if (w > 0) add += wsum[0];
            if (w > 1) add += wsum[1];
            if (w > 2) add += wsum[2];
            dsum[t] += add;                      // global exclusive digit base
        }
        __syncthreads();
        // fold digit base into per-wave bases: wcnt[w][d] += dsum[d]
#pragma unroll
        for (int i = 0; i < 4; ++i) {
            int id = t + T * i;
            wcnt[id] += dsum[id & 255];
        }
        __syncthreads();

        // ---- scatter ----
#pragma unroll
        for (int j = 0; j < 16; ++j) {
            u32 d = (u32)(key[j] >> shift) & 255u;
            rank[j] += wcnt[(w << 8) | d];       // final position
        }
#pragma unroll
        for (int j = 0; j < 16; ++j) data[rank[j]] = key[j];
        __syncthreads();

        if (p < 3) {
#pragma unroll
            for (int j = 0; j < 16; ++j) {
                int e = (w << 10) | (j << 6) | lane;
                key[j] = data[e];
            }
        }
    }

    // ---- outputs: data[] sorted ascending in enc == descending in x ----
    float* bcr = bc + (size_t)row * N;
    float* ixr = idx_out + (size_t)row * N;
#pragma unroll
    for (int j = 0; j < 16; ++j) {
        int e = (w << 10) | (j << 6) | lane;     // per-slot coalesced stores
        u64 kk = data[e];
        ixr[e] = (float)(u32)(kk & 0xFFFFFFFFu);
        bcr[e] = 0.0f;
    }
    // winner: threads 0..6 each redundantly compute softmax(top-7), write own slot.
    // Overwrites this thread's own j=0 zero-write (same thread, program order: safe).
    if (t < G) {
        float s[G], ex[G], sum = 0.f;
#pragma unroll
        for (int g = 0; g < G; ++g) s[g] = dec_desc((u32)(data[g] >> 32));
        float m0 = s[0];                          // max (descending values)
#pragma unroll
        for (int g = 0; g < G; ++g) { ex[g] = expf(s[g] - m0); sum += ex[g]; }
        bcr[t] = ex[t] / sum;
    }
    // loser: threads 505..511 (w=7, j=15 slots) -> positions N-G..N-1.
    // -softmax(1 - bottom) == -softmax(-bottom) (shift invariance)
    if (t >= T - G) {
        float s[G], ex[G], sum = 0.f;
#pragma unroll
        for (int g = 0; g < G; ++g) s[g] = dec_desc((u32)(data[N - G + g] >> 32));
        float m0 = -s[G - 1];                     // max of -s (s descending)
#pragma unroll
        for (int g = 0; g < G; ++g) { ex[g] = expf(-s[g] - m0); sum += ex[g]; }
        bcr[(N - T) + t] = -ex[t - (T - G)] / sum;
    }
}

extern "C" void kernel_launch(void* const* d_in, const int* in_sizes, int n_in,
                              void* d_out, int out_size, void* d_ws, size_t ws_size,
                              hipStream_t stream) {
    const float* x = (const float*)d_in[0];
    float* out = (float*)d_out;
    const int B = in_sizes[0] / N;               // 4096
    float* bc  = out;                             // output 0: [B, N]
    float* idx = out + (size_t)B * N;             // output 1: [B, N] (as float32)
    portfolio_radix_kernel<<<B, T, 0, stream>>>(x, bc, idx);
}